// Round 12
// baseline (172.105 us; speedup 1.0000x reference)
//
#include <hip/hip_runtime.h>
#include <type_traits>

#define RES_ 0.16f
#define XMIN_ -51.2f
#define YMIN_ -51.2f
#define EPS_ 1e-5f
#define NEG_ -1000000000.0f

#define WPB 4  // waves per block

typedef _Float16 f16x8 __attribute__((ext_vector_type(8)));
typedef _Float16 f16x4 __attribute__((ext_vector_type(4)));
typedef _Float16 f16x2 __attribute__((ext_vector_type(2)));
typedef float f32x4 __attribute__((ext_vector_type(4)));

union F8u { f16x8 v; f16x2 h[4]; };
union F4u { f16x4 v; f16x2 h[2]; };

// cvt_pkrtz returns __fp16x2 on this clang; launder to _Float16x2 (same bits)
static __device__ __forceinline__ f16x2 pkrtz(float a, float b) {
    return __builtin_bit_cast(f16x2, __builtin_amdgcn_cvt_pkrtz(a, b));
}

static __device__ __forceinline__ f16x2 relu2(f16x2 x) {
#if __has_builtin(__builtin_elementwise_max)
    const f16x2 z2 = (f16x2)(_Float16)0.f;
    return __builtin_elementwise_max(x, z2);   // v_pk_max_f16
#else
    f16x2 r;
    r[0] = x[0] > (_Float16)0.f ? x[0] : (_Float16)0.f;
    r[1] = x[1] > (_Float16)0.f ? x[1] : (_Float16)0.f;
    return r;
#endif
}

// NOTE (r11): zero-LDS dataflow — layer-1 computed transposed (W1^T @ feat^T) so
// its MFMA C-output IS layer-2's A-operand under a W2 k-row permutation
// c(kt,quad,j)=32kt+16(j>>2)+4quad+(j&3). No LDS staging, no h1 round-trip.
// NOTE (r12): z_mean pipelined one pillar ahead (its 4-deep shuffle chain overlaps
// the previous body); trying the 5-wave tier now that the kernel is lean.
// Tripwire: WRITE_SIZE >> 25MB means the 102-reg cap spilled (r9 signature).
__global__ __launch_bounds__(256, 5) void pfn_kernel(
    const float* __restrict__ pillars,
    const int* __restrict__ coords,
    const int* __restrict__ npts_arr,
    const float* __restrict__ W1, const float* __restrict__ b1,
    const float* __restrict__ g1, const float* __restrict__ beta1,
    const float* __restrict__ m1, const float* __restrict__ v1,
    const float* __restrict__ W2, const float* __restrict__ b2,
    const float* __restrict__ g2, const float* __restrict__ beta2,
    const float* __restrict__ m2, const float* __restrict__ v2,
    float* __restrict__ out, int P)
{
    const int tid  = threadIdx.x;
    const int wave = tid >> 6;
    const int lane = tid & 63;
    const int quad = lane >> 4;
    const int col  = lane & 15;

    // ---- W1^T as layer-1 A-frags (K padded 9->16), BN1 scale+bias+z folded ----
    // A[m = mtile*16+col (channel)][k = quad*4+j (feat slot)]
    // slots: {x,y,z,r,xo,yo,z,xo,yo, 1.0(bias), -z_mean(w6 again), 0...}
    f16x4 aw1[4];
#pragma unroll
    for (int mt = 0; mt < 4; ++mt) {
        const int ch = mt * 16 + col;
        const float a1 = g1[ch] * rsqrtf(v1[ch] + EPS_);
        const float c1 = fmaf(a1, b1[ch] - m1[ch], beta1[ch]);
#pragma unroll
        for (int j = 0; j < 4; ++j) {
            const int k = quad * 4 + j;
            float w;
            if (k < 9)        w = a1 * W1[k * 64 + ch];
            else if (k == 9)  w = c1;                      // bias slot (feat=1.0)
            else if (k == 10) w = a1 * W1[6 * 64 + ch];    // z_mean slot (feat=-zm)
            else              w = 0.0f;
            aw1[mt][j] = (_Float16)w;
        }
    }

    // ---- W2 (BN2-scale folded), k-rows permuted to match in-register h1 layout ----
    f16x8 bw2[2][4];
#pragma unroll
    for (int nt = 0; nt < 4; ++nt) {
        const int n0 = nt * 16 + col;
        const float a2 = g2[n0] * rsqrtf(v2[n0] + EPS_);
#pragma unroll
        for (int kt = 0; kt < 2; ++kt)
#pragma unroll
            for (int j = 0; j < 8; ++j) {
                const int c = 32 * kt + 16 * (j >> 2) + 4 * quad + (j & 3);
                bw2[kt][nt][j] = (_Float16)(a2 * W2[c * 64 + n0]);
            }
    }
    // lane's own output-channel bias (applied AFTER the row-max; max is shift-equivariant)
    const float c2own = fmaf(g2[lane] * rsqrtf(v2[lane] + EPS_),
                             b2[lane] - m2[lane], beta2[lane]);

    // z reduction helper: sum valid z over 16-col groups (quads replicate)
    auto zreduce = [&](const float4& A, const float4& B, int n) -> float {
        float zs = (col < n) ? A.z : 0.0f;
        zs += (16 + col < n) ? B.z : 0.0f;
#pragma unroll
        for (int off = 1; off <= 8; off <<= 1) zs += __shfl_xor(zs, off, 64);
        return zs / fmaxf((float)n, 1.0f);
    };

    const int nwaves = gridDim.x * WPB;
    int p = __builtin_amdgcn_readfirstlane(blockIdx.x * WPB + wave);
    if (p >= P) return;

    // ---- preamble: load + z for pillar 0 ----
    const float4* pb = (const float4*)(pillars + (size_t)p * 128);
    float4 ptA = pb[col];
    float4 ptB = pb[16 + col];
    int np = npts_arr[p];
    int cy = coords[2 * p], cx = coords[2 * p + 1];
    np = np < 0 ? 0 : (np > 32 ? 32 : np);
    float z_cur = zreduce(ptA, ptB, np);

    while (true) {
        const int pn = p + nwaves;
        const bool has_next = pn < P;
        float4 ptAn, ptBn; int npn = 0, cyn = 0, cxn = 0;
        if (has_next) {                       // wave-uniform; issue loads early
            const float4* pbn = (const float4*)(pillars + (size_t)pn * 128);
            ptAn = pbn[col];
            ptBn = pbn[16 + col];
            npn = npts_arr[pn];
            cyn = coords[2 * pn]; cxn = coords[2 * pn + 1];
        }

        const int npu = __builtin_amdgcn_readfirstlane(np);
        const float xc = ((float)cx + 0.5f) * RES_ + XMIN_;
        const float yc = ((float)cy + 0.5f) * RES_ + YMIN_;
        const float z_mean = z_cur;

        // ================= pillar body (zero LDS) =================
        auto body = [&](auto MTC) -> float {
            constexpr int MT = decltype(MTC)::value;
            float hm4[4] = {NEG_, NEG_, NEG_, NEG_};

#pragma unroll
            for (int t = 0; t < MT; ++t) {
                const float4 pt = (t == 0) ? ptA : ptB;

                // ---- feat^T B-frag: B[k=quad*4+j][n=point col] ----
                const float xo = pt.x - xc;
                const float yo = pt.y - yc;
                const f16x2 c01 = pkrtz(pt.x, pt.y);       // quad0: x,y
                const f16x2 c23 = pkrtz(pt.z, pt.w);       // quad0: z,r
                const f16x2 c45 = pkrtz(xo, yo);           // quad1: xo,yo
                const f16x2 c67 = pkrtz(pt.z, xo);         // quad1: z(slot6), xo
                const f16x2 c89 = pkrtz(yo, 1.0f);         // quad2: yo, bias-1
                const f16x2 cab = pkrtz(-z_mean, 0.0f);    // quad2: -zm, 0
                const f16x2 z2  = (f16x2)(_Float16)0.f;
                F4u u;
                u.h[0] = (quad == 0) ? c01 : (quad == 1) ? c45 : (quad == 2) ? c89 : z2;
                u.h[1] = (quad == 0) ? c23 : (quad == 1) ? c67 : (quad == 2) ? cab : z2;
                const f16x4 bt = u.v;

                // ---- layer-1: 4 MFMAs, C=0 (bias+z in K-slots) ----
                f32x4 acc1[4];
                const f32x4 zz = {0.f, 0.f, 0.f, 0.f};
#pragma unroll
                for (int mt = 0; mt < 4; ++mt)
                    acc1[mt] = __builtin_amdgcn_mfma_f32_16x16x16f16(aw1[mt], bt, zz, 0, 0, 0);

                // ---- h1 relu + pack: layer-2 A-frags, pure in-lane ----
                f16x8 av2[2];
#pragma unroll
                for (int kt = 0; kt < 2; ++kt) {
                    F8u w;
                    w.h[0] = relu2(pkrtz(acc1[2 * kt][0],     acc1[2 * kt][1]));
                    w.h[1] = relu2(pkrtz(acc1[2 * kt][2],     acc1[2 * kt][3]));
                    w.h[2] = relu2(pkrtz(acc1[2 * kt + 1][0], acc1[2 * kt + 1][1]));
                    w.h[3] = relu2(pkrtz(acc1[2 * kt + 1][2], acc1[2 * kt + 1][3]));
                    av2[kt] = w.v;
                }

                // ---- row-mask as layer-2 C-init (free adds) ----
                f32x4 cm;
#pragma unroll
                for (int r = 0; r < 4; ++r)
                    cm[r] = (t * 16 + quad * 4 + r < np) ? 0.0f : NEG_;

                // ---- layer-2: stream per nt, fold into running max ----
#pragma unroll
                for (int nt = 0; nt < 4; ++nt) {
                    f32x4 acc = __builtin_amdgcn_mfma_f32_16x16x32_f16(av2[0], bw2[0][nt], cm, 0, 0, 0);
                    acc = __builtin_amdgcn_mfma_f32_16x16x32_f16(av2[1], bw2[1][nt], acc, 0, 0, 0);
                    hm4[nt] = fmaxf(fmaxf(hm4[nt], fmaxf(acc[0], acc[1])),
                                    fmaxf(acc[2], acc[3]));   // max3-formable
                }
            }

            // ---- cross-quad max, select own channel, bias+relu ----
            float hmv[4];
#pragma unroll
            for (int nt = 0; nt < 4; ++nt) {
                float hm = hm4[nt];
                hm = fmaxf(hm, __shfl_xor(hm, 16, 64));
                hm = fmaxf(hm, __shfl_xor(hm, 32, 64));
                hmv[nt] = hm;
            }
            float r0 = (quad == 0) ? hmv[0] : (quad == 1) ? hmv[1] : (quad == 2) ? hmv[2] : hmv[3];
            return fmaxf(r0 + c2own, 0.0f);
        };

        float res;
        if (npu > 16)     res = body(std::integral_constant<int, 2>{});
        else if (npu > 0) res = body(std::integral_constant<int, 1>{});
        else              res = NEG_;
        out[(size_t)p * 64 + lane] = res;

        if (!has_next) break;

        // ---- pipelined: z for NEXT pillar (shuffle chain overlaps MFMA drain) ----
        npn = npn < 0 ? 0 : (npn > 32 ? 32 : npn);
        z_cur = zreduce(ptAn, ptBn, npn);

        p = pn; ptA = ptAn; ptB = ptBn; np = npn; cy = cyn; cx = cxn;
    }
}

extern "C" void kernel_launch(void* const* d_in, const int* in_sizes, int n_in,
                              void* d_out, int out_size, void* d_ws, size_t ws_size,
                              hipStream_t stream) {
    const float* pillars = (const float*)d_in[0];
    const int*   coords  = (const int*)d_in[1];
    const int*   npts    = (const int*)d_in[2];
    const float* W1      = (const float*)d_in[3];
    const float* b1      = (const float*)d_in[4];
    const float* g1      = (const float*)d_in[5];
    const float* beta1   = (const float*)d_in[6];
    const float* m1      = (const float*)d_in[7];
    const float* v1      = (const float*)d_in[8];
    const float* W2      = (const float*)d_in[9];
    const float* b2      = (const float*)d_in[10];
    const float* g2      = (const float*)d_in[11];
    const float* beta2   = (const float*)d_in[12];
    const float* m2      = (const float*)d_in[13];
    const float* v2      = (const float*)d_in[14];
    float* out           = (float*)d_out;

    const int P = in_sizes[2];
    // 1280 blocks = 5 blocks/CU resident at 5 waves/SIMD (launch_bounds 256,5); zero LDS
    const int blocks = 1280;

    hipLaunchKernelGGL(pfn_kernel, dim3(blocks), dim3(256), 0, stream,
                       pillars, coords, npts, W1, b1, g1, beta1, m1, v1,
                       W2, b2, g2, beta2, m2, v2, out, P);
}

// Round 13
// 149.760 us; speedup vs baseline: 1.1492x; 1.1492x over previous
//
#include <hip/hip_runtime.h>
#include <type_traits>

#define RES_ 0.16f
#define XMIN_ -51.2f
#define YMIN_ -51.2f
#define EPS_ 1e-5f
#define NEG_ -1000000000.0f

#define WPB 4  // waves per block

typedef _Float16 f16x8 __attribute__((ext_vector_type(8)));
typedef _Float16 f16x4 __attribute__((ext_vector_type(4)));
typedef _Float16 f16x2 __attribute__((ext_vector_type(2)));
typedef float f32x4 __attribute__((ext_vector_type(4)));

union F8u { f16x8 v; f16x2 h[4]; };
union F4u { f16x4 v; f16x2 h[2]; };

// cvt_pkrtz returns __fp16x2 on this clang; launder to _Float16x2 (same bits)
static __device__ __forceinline__ f16x2 pkrtz(float a, float b) {
    return __builtin_bit_cast(f16x2, __builtin_amdgcn_cvt_pkrtz(a, b));
}

static __device__ __forceinline__ f16x2 relu2(f16x2 x) {
#if __has_builtin(__builtin_elementwise_max)
    const f16x2 z2 = (f16x2)(_Float16)0.f;
    return __builtin_elementwise_max(x, z2);   // v_pk_max_f16
#else
    f16x2 r;
    r[0] = x[0] > (_Float16)0.f ? x[0] : (_Float16)0.f;
    r[1] = x[1] > (_Float16)0.f ? x[1] : (_Float16)0.f;
    return r;
#endif
}

static __device__ __forceinline__ float fast_rcp(float x) {
#if __has_builtin(__builtin_amdgcn_rcpf)
    return __builtin_amdgcn_rcpf(x);   // v_rcp_f32, ~1ulp — fine at f16 downstream
#else
    return 1.0f / x;
#endif
}

// NOTE (r11): zero-LDS dataflow — layer-1 computed transposed (W1^T @ feat^T) so
// its MFMA C-output IS layer-2's A-operand under a W2 k-row permutation
// c(kt,quad,j)=32kt+16(j>>2)+4quad+(j&3). No LDS staging, no h1 round-trip.
// NOTE (r9+r12, PINNED): this kernel needs the 128-unified-reg tier. Both
// 5-wave attempts (launch_bounds(256,5)) spilled to scratch (WRITE_SIZE
// 25->47MB r9, 25->38MB r12). Keep (256,4). Do not retry.
// NOTE (r13): z_mean pipelined one pillar ahead; division -> v_rcp_f32.
__global__ __launch_bounds__(256, 4) void pfn_kernel(
    const float* __restrict__ pillars,
    const int* __restrict__ coords,
    const int* __restrict__ npts_arr,
    const float* __restrict__ W1, const float* __restrict__ b1,
    const float* __restrict__ g1, const float* __restrict__ beta1,
    const float* __restrict__ m1, const float* __restrict__ v1,
    const float* __restrict__ W2, const float* __restrict__ b2,
    const float* __restrict__ g2, const float* __restrict__ beta2,
    const float* __restrict__ m2, const float* __restrict__ v2,
    float* __restrict__ out, int P)
{
    const int tid  = threadIdx.x;
    const int wave = tid >> 6;
    const int lane = tid & 63;
    const int quad = lane >> 4;
    const int col  = lane & 15;

    // ---- W1^T as layer-1 A-frags (K padded 9->16), BN1 scale+bias+z folded ----
    // A[m = mtile*16+col (channel)][k = quad*4+j (feat slot)]
    // slots: {x,y,z,r,xo,yo,z,xo,yo, 1.0(bias), -z_mean(w6 again), 0...}
    f16x4 aw1[4];
#pragma unroll
    for (int mt = 0; mt < 4; ++mt) {
        const int ch = mt * 16 + col;
        const float a1 = g1[ch] * rsqrtf(v1[ch] + EPS_);
        const float c1 = fmaf(a1, b1[ch] - m1[ch], beta1[ch]);
#pragma unroll
        for (int j = 0; j < 4; ++j) {
            const int k = quad * 4 + j;
            float w;
            if (k < 9)        w = a1 * W1[k * 64 + ch];
            else if (k == 9)  w = c1;                      // bias slot (feat=1.0)
            else if (k == 10) w = a1 * W1[6 * 64 + ch];    // z_mean slot (feat=-zm)
            else              w = 0.0f;
            aw1[mt][j] = (_Float16)w;
        }
    }

    // ---- W2 (BN2-scale folded), k-rows permuted to match in-register h1 layout ----
    f16x8 bw2[2][4];
#pragma unroll
    for (int nt = 0; nt < 4; ++nt) {
        const int n0 = nt * 16 + col;
        const float a2 = g2[n0] * rsqrtf(v2[n0] + EPS_);
#pragma unroll
        for (int kt = 0; kt < 2; ++kt)
#pragma unroll
            for (int j = 0; j < 8; ++j) {
                const int c = 32 * kt + 16 * (j >> 2) + 4 * quad + (j & 3);
                bw2[kt][nt][j] = (_Float16)(a2 * W2[c * 64 + n0]);
            }
    }
    // lane's own output-channel bias (applied AFTER the row-max; max is shift-equivariant)
    const float c2own = fmaf(g2[lane] * rsqrtf(v2[lane] + EPS_),
                             b2[lane] - m2[lane], beta2[lane]);

    // z reduction: sum valid z over 16-col groups (quads replicate), mean via rcp
    auto zreduce = [&](const float4& A, const float4& B, int n) -> float {
        float zs = (col < n) ? A.z : 0.0f;
        zs += (16 + col < n) ? B.z : 0.0f;
#pragma unroll
        for (int off = 1; off <= 8; off <<= 1) zs += __shfl_xor(zs, off, 64);
        return zs * fast_rcp(fmaxf((float)n, 1.0f));
    };

    const int nwaves = gridDim.x * WPB;
    int p = __builtin_amdgcn_readfirstlane(blockIdx.x * WPB + wave);
    if (p >= P) return;

    // ---- preamble: load + z for pillar 0 ----
    const float4* pb = (const float4*)(pillars + (size_t)p * 128);
    float4 ptA = pb[col];
    float4 ptB = pb[16 + col];
    int np = npts_arr[p];
    int cy = coords[2 * p], cx = coords[2 * p + 1];
    np = np < 0 ? 0 : (np > 32 ? 32 : np);
    float z_cur = zreduce(ptA, ptB, np);

    while (true) {
        const int pn = p + nwaves;
        const bool has_next = pn < P;
        float4 ptAn, ptBn; int npn = 0, cyn = 0, cxn = 0;
        if (has_next) {                       // wave-uniform; issue loads early
            const float4* pbn = (const float4*)(pillars + (size_t)pn * 128);
            ptAn = pbn[col];
            ptBn = pbn[16 + col];
            npn = npts_arr[pn];
            cyn = coords[2 * pn]; cxn = coords[2 * pn + 1];
        }

        const int npu = __builtin_amdgcn_readfirstlane(np);
        const float xc = ((float)cx + 0.5f) * RES_ + XMIN_;
        const float yc = ((float)cy + 0.5f) * RES_ + YMIN_;
        const float z_mean = z_cur;

        // ================= pillar body (zero LDS) =================
        auto body = [&](auto MTC) -> float {
            constexpr int MT = decltype(MTC)::value;
            float hm4[4] = {NEG_, NEG_, NEG_, NEG_};

#pragma unroll
            for (int t = 0; t < MT; ++t) {
                const float4 pt = (t == 0) ? ptA : ptB;

                // ---- feat^T B-frag: B[k=quad*4+j][n=point col] ----
                const float xo = pt.x - xc;
                const float yo = pt.y - yc;
                const f16x2 c01 = pkrtz(pt.x, pt.y);       // quad0: x,y
                const f16x2 c23 = pkrtz(pt.z, pt.w);       // quad0: z,r
                const f16x2 c45 = pkrtz(xo, yo);           // quad1: xo,yo
                const f16x2 c67 = pkrtz(pt.z, xo);         // quad1: z(slot6), xo
                const f16x2 c89 = pkrtz(yo, 1.0f);         // quad2: yo, bias-1
                const f16x2 cab = pkrtz(-z_mean, 0.0f);    // quad2: -zm, 0
                const f16x2 z2  = (f16x2)(_Float16)0.f;
                F4u u;
                u.h[0] = (quad == 0) ? c01 : (quad == 1) ? c45 : (quad == 2) ? c89 : z2;
                u.h[1] = (quad == 0) ? c23 : (quad == 1) ? c67 : (quad == 2) ? cab : z2;
                const f16x4 bt = u.v;

                // ---- layer-1: 4 MFMAs, C=0 (bias+z in K-slots) ----
                f32x4 acc1[4];
                const f32x4 zz = {0.f, 0.f, 0.f, 0.f};
#pragma unroll
                for (int mt = 0; mt < 4; ++mt)
                    acc1[mt] = __builtin_amdgcn_mfma_f32_16x16x16f16(aw1[mt], bt, zz, 0, 0, 0);

                // ---- h1 relu + pack: layer-2 A-frags, pure in-lane ----
                f16x8 av2[2];
#pragma unroll
                for (int kt = 0; kt < 2; ++kt) {
                    F8u w;
                    w.h[0] = relu2(pkrtz(acc1[2 * kt][0],     acc1[2 * kt][1]));
                    w.h[1] = relu2(pkrtz(acc1[2 * kt][2],     acc1[2 * kt][3]));
                    w.h[2] = relu2(pkrtz(acc1[2 * kt + 1][0], acc1[2 * kt + 1][1]));
                    w.h[3] = relu2(pkrtz(acc1[2 * kt + 1][2], acc1[2 * kt + 1][3]));
                    av2[kt] = w.v;
                }

                // ---- row-mask as layer-2 C-init (free adds) ----
                f32x4 cm;
#pragma unroll
                for (int r = 0; r < 4; ++r)
                    cm[r] = (t * 16 + quad * 4 + r < np) ? 0.0f : NEG_;

                // ---- layer-2: stream per nt, fold into running max ----
#pragma unroll
                for (int nt = 0; nt < 4; ++nt) {
                    f32x4 acc = __builtin_amdgcn_mfma_f32_16x16x32_f16(av2[0], bw2[0][nt], cm, 0, 0, 0);
                    acc = __builtin_amdgcn_mfma_f32_16x16x32_f16(av2[1], bw2[1][nt], acc, 0, 0, 0);
                    hm4[nt] = fmaxf(fmaxf(hm4[nt], fmaxf(acc[0], acc[1])),
                                    fmaxf(acc[2], acc[3]));   // max3-formable
                }
            }

            // ---- cross-quad max, select own channel, bias+relu ----
            float hmv[4];
#pragma unroll
            for (int nt = 0; nt < 4; ++nt) {
                float hm = hm4[nt];
                hm = fmaxf(hm, __shfl_xor(hm, 16, 64));
                hm = fmaxf(hm, __shfl_xor(hm, 32, 64));
                hmv[nt] = hm;
            }
            float r0 = (quad == 0) ? hmv[0] : (quad == 1) ? hmv[1] : (quad == 2) ? hmv[2] : hmv[3];
            return fmaxf(r0 + c2own, 0.0f);
        };

        float res;
        if (npu > 16)     res = body(std::integral_constant<int, 2>{});
        else if (npu > 0) res = body(std::integral_constant<int, 1>{});
        else              res = NEG_;
        out[(size_t)p * 64 + lane] = res;

        if (!has_next) break;

        // ---- pipelined: z for NEXT pillar (shuffle chain overlaps MFMA drain) ----
        npn = npn < 0 ? 0 : (npn > 32 ? 32 : npn);
        z_cur = zreduce(ptAn, ptBn, npn);

        p = pn; ptA = ptAn; ptB = ptBn; np = npn; cy = cyn; cx = cxn;
    }
}

extern "C" void kernel_launch(void* const* d_in, const int* in_sizes, int n_in,
                              void* d_out, int out_size, void* d_ws, size_t ws_size,
                              hipStream_t stream) {
    const float* pillars = (const float*)d_in[0];
    const int*   coords  = (const int*)d_in[1];
    const int*   npts    = (const int*)d_in[2];
    const float* W1      = (const float*)d_in[3];
    const float* b1      = (const float*)d_in[4];
    const float* g1      = (const float*)d_in[5];
    const float* beta1   = (const float*)d_in[6];
    const float* m1      = (const float*)d_in[7];
    const float* v1      = (const float*)d_in[8];
    const float* W2      = (const float*)d_in[9];
    const float* b2      = (const float*)d_in[10];
    const float* g2      = (const float*)d_in[11];
    const float* beta2   = (const float*)d_in[12];
    const float* m2      = (const float*)d_in[13];
    const float* v2      = (const float*)d_in[14];
    float* out           = (float*)d_out;

    const int P = in_sizes[2];
    // 1024 blocks = 4 blocks/CU resident at 4 waves/SIMD (launch_bounds 256,4); zero LDS
    const int blocks = 1024;

    hipLaunchKernelGGL(pfn_kernel, dim3(blocks), dim3(256), 0, stream,
                       pillars, coords, npts, W1, b1, g1, beta1, m1, v1,
                       W2, b2, g2, beta2, m2, v2, out, P);
}